// Round 12
// baseline (299.288 us; speedup 1.0000x reference)
//
#include <hip/hip_runtime.h>

typedef short short8 __attribute__((ext_vector_type(8)));
typedef float f32x4 __attribute__((ext_vector_type(4)));

#define NROWS 32768
#define DIM 32
#define KCODES 8192
#define FLAG_CAP 16384
#define FLAG_EPS 4.0e-4f   // abs margin on packed biased scores; covers split err
                           // (~3e-5 worst) + 2x 5-bit pack (1.2e-4), 2.5x headroom

// ws layout (bytes)
#define WS_EHI  0
#define WS_ELO  (512*1024)
#define WS_PART (1024*1024)            // 1024 floats (gather block partials; 512 used)
#define WS_CNT  (WS_PART + 4096)       // cnt[0]=flag count, cnt[1]=refine ticket
#define WS_LIST (WS_CNT + 64)          // FLAG_CAP ints
#define WS_CORR (WS_LIST + FLAG_CAP*4) // FLAG_CAP floats

__device__ __forceinline__ unsigned short bf16_rne(float v){
    unsigned int u = __float_as_uint(v);
    unsigned int r = (u + 0x7fffu + ((u >> 16) & 1u)) >> 16;
    return (unsigned short)r;
}
__device__ __forceinline__ float bf16_to_f(unsigned short h){
    return __uint_as_float(((unsigned int)h) << 16);
}
__device__ __forceinline__ float dot4(const float4& a, const float4& b){
    return fmaf(a.w, b.w, fmaf(a.z, b.z, fmaf(a.y, b.y, a.x * b.x)));
}

// ------------- prep: codebook hi/lo bf16 split (thread = code x quarter) -----
__global__ __launch_bounds__(256) void vq_prep(
    const float* __restrict__ emb,
    unsigned short* __restrict__ ehi, unsigned short* __restrict__ elo,
    int* __restrict__ cnt)
{
    int tid = blockIdx.x * 256 + threadIdx.x;   // 0..32767
    if (tid < 2) cnt[tid] = 0;
    int r  = tid >> 2;
    int qt = tid & 3;
    const float* er = emb + (size_t)r * DIM + qt * 8;
    float4 v0 = *(const float4*)er;
    float4 v1 = *(const float4*)(er + 4);
    float f[8] = {v0.x, v0.y, v0.z, v0.w, v1.x, v1.y, v1.z, v1.w};
    short8 a, b;
    #pragma unroll
    for (int j = 0; j < 8; j++){
        unsigned short h = bf16_rne(f[j]);
        a[j] = (short)h;
        b[j] = (short)bf16_rne(f[j] - bf16_to_f(h));
    }
    *(short8*)(ehi + (size_t)r * DIM + qt * 8) = a;
    *(short8*)(elo + (size_t)r * DIM + qt * 8) = b;
}

// ---------------- main: MFMA argmax scan, candidates -> out_q stash ----------
// 1024 blocks = 512 row-sets x 2 code-halves; 8 waves; 64 rows/block
// (4 rowgroups = 24 MFMA per 4 B-loads — R7 proved halving this is 1.5x worse).
// Wave w scans codes [half*4096 + w*512, +512) = 32 tiles of 16. Constant bias
// 16 in MFMA C keeps scores positive (norm <= ~8.5) so packed
// (score & ~31 | 31-t) uints order correctly with first-occurrence tie-break.
// NOTE: min-waves stays 4 (R6: forcing 8 spills); no reg prefetch (R8: spill);
// no global_load_lds DMA (R9: occupancy collapse); grid size is perf-neutral
// (R5 512blk == R11 1024blk) — main is per-score-throughput-limited.
#define PROC(bhv, blv, tcs)                                                      \
  {                                                                              \
    unsigned int tcv = (unsigned int)(tcs);                                      \
    _Pragma("unroll")                                                            \
    for (int rg = 0; rg < 4; ++rg){                                              \
      f32x4 acc = __builtin_amdgcn_mfma_f32_16x16x32_bf16(ahi[rg], bhv, c16, 0, 0, 0); \
      acc = __builtin_amdgcn_mfma_f32_16x16x32_bf16(ahi[rg], blv, acc, 0, 0, 0); \
      acc = __builtin_amdgcn_mfma_f32_16x16x32_bf16(alo[rg], bhv, acc, 0, 0, 0); \
      _Pragma("unroll")                                                          \
      for (int q = 0; q < 4; ++q){                                               \
        unsigned int u = (__float_as_uint(acc[q]) & maskv) | tcv;                \
        int rr = rg * 4 + q;                                                     \
        unsigned int nv2;                                                        \
        asm("v_med3_u32 %0, %1, %2, %3" : "=v"(nv2) : "v"(u), "v"(v1[rr]), "v"(v2[rr])); \
        v2[rr] = nv2;                                                            \
        v1[rr] = max(u, v1[rr]);                                                 \
      }                                                                          \
    }                                                                            \
  }

__global__ __launch_bounds__(512, 4) void vq_main_mfma(
    const float* __restrict__ inputs,
    const unsigned short* __restrict__ ehi,
    const unsigned short* __restrict__ elo,
    unsigned int* __restrict__ qscr)   // = (u32*)out_q; 6 words per row span
{
    const int L = threadIdx.x & 63;
    const int w = threadIdx.x >> 6;
    const int half_ = blockIdx.x >> 9;
    const int rowbase = (blockIdx.x & 511) * 64;

    __shared__ unsigned int sv1[8][64];
    __shared__ unsigned int sv2[8][64];
    __shared__ int          scol[8][64];

    // A fragments (all waves load the same 64 rows)
    short8 ahi[4], alo[4];
    #pragma unroll
    for (int rg = 0; rg < 4; ++rg){
        const float* xr = inputs + (size_t)(rowbase + rg*16 + (L & 15)) * DIM + (L >> 4) * 8;
        float4 p0 = *(const float4*)xr;
        float4 p1 = *(const float4*)(xr + 4);
        float f[8] = {p0.x, p0.y, p0.z, p0.w, p1.x, p1.y, p1.z, p1.w};
        short8 h, l;
        #pragma unroll
        for (int i = 0; i < 8; i++){
            unsigned short hb = bf16_rne(f[i]);
            h[i] = (short)hb;
            l[i] = (short)bf16_rne(f[i] - bf16_to_f(hb));
        }
        ahi[rg] = h; alo[rg] = l;
    }

    const f32x4 c16 = {16.0f, 16.0f, 16.0f, 16.0f};   // bias: |dot| <= norm <= ~8.5

    unsigned int maskv = 0xFFFFFFE0u;   // 5-bit counter field (t < 32)
    asm("" : "+v"(maskv));   // pin mask in VGPR so (x & m) | t fuses to v_and_or_b32

    unsigned int v1[16], v2[16];
    #pragma unroll
    for (int r = 0; r < 16; r++){ v1[r] = 0u; v2[r] = 0u; }

    const int c0 = half_ * 4096 + w * 512;
    const unsigned short* ehp = ehi + (size_t)(c0 + (L & 15)) * DIM + (L >> 4) * 8;
    const unsigned short* elp = elo + (size_t)(c0 + (L & 15)) * DIM + (L >> 4) * 8;

    for (int t = 0; t < 32; t += 2){
        short8 b0h = *(const short8*)(ehp);
        short8 b0l = *(const short8*)(elp);
        short8 b1h = *(const short8*)(ehp + 512);
        short8 b1l = *(const short8*)(elp + 512);
        ehp += 1024; elp += 1024;
        PROC(b0h, b0l, 31 - t);
        PROC(b1h, b1l, 30 - t);
    }

    // in-register reduction over the 16 cols (lane&15), exact top-2 merge
    unsigned int p1[16];
    #pragma unroll
    for (int r = 0; r < 16; r++) p1[r] = v1[r];
    #pragma unroll
    for (int m = 1; m < 16; m <<= 1){
        #pragma unroll
        for (int r = 0; r < 16; r++){
            unsigned int ov1 = __shfl_xor(v1[r], m, 64);
            unsigned int ov2 = __shfl_xor(v2[r], m, 64);
            unsigned int mn = min(v1[r], ov1);
            v2[r] = max(max(v2[r], ov2), mn);
            v1[r] = max(v1[r], ov1);
        }
    }
    // recover winning col via ballot (lowest matching lane = lowest col = first occurrence)
    int colr[16];
    #pragma unroll
    for (int r = 0; r < 16; r++){
        unsigned long long bm = __ballot(p1[r] == v1[r]);
        unsigned int grp = (unsigned int)((bm >> ((L >> 4) << 4)) & 0xFFFFull);
        colr[r] = __ffs(grp) - 1;
    }

    if ((L & 15) == 0){
        #pragma unroll
        for (int rg = 0; rg < 4; ++rg){
            #pragma unroll
            for (int q = 0; q < 4; ++q){
                int row = rg*16 + (L >> 4)*4 + q;   // C row = (lane>>4)*4 + reg
                sv1[w][row] = v1[rg*4 + q];
                sv2[w][row] = v2[rg*4 + q];
                scol[w][row] = colr[rg*4 + q];
            }
        }
    }
    __syncthreads();

    // epilogue (threads 0..63): merge 8 wave-slices, write (b1,b2,k) stash
    if (threadIdx.x < 64){
        int r = threadIdx.x;
        unsigned int b1 = 0u, b2 = 0u; int bw = 0, bc = 0;
        #pragma unroll
        for (int s = 0; s < 8; ++s){
            unsigned int u1 = sv1[s][r];
            unsigned int u2 = sv2[s][r];
            unsigned int mn = min(b1, u1);
            b2 = max(max(b2, u2), mn);
            bool g = u1 > b1;
            if (g){ b1 = u1; bw = s; bc = scol[s][r]; }
        }
        int t = 31 - (int)(b1 & 31u);
        int k = half_*4096 + bw*512 + t*16 + bc;
        unsigned int* qs = qscr + (size_t)(rowbase + r) * 32 + half_ * 3;
        qs[0] = b1; qs[1] = b2; qs[2] = (unsigned int)k;
    }
}

// -------- gather: 4 threads/row — merge halves, gather, loss, flag -----------
__global__ __launch_bounds__(256) void vq_gather(
    const float* __restrict__ inputs, const float* __restrict__ emb,
    float* __restrict__ out_q, float* __restrict__ out_idx,
    float* __restrict__ part, int* __restrict__ cnt, int* __restrict__ list)
{
    const int tid = blockIdx.x * 256 + threadIdx.x;   // 0..131071
    const int row = tid >> 2;
    const int qt  = tid & 3;
    const int L   = threadIdx.x & 63;
    unsigned int* q32 = (unsigned int*)out_q;

    int k = 0;
    bool flag = false;
    if (qt == 0){
        unsigned int a1 = q32[(size_t)row*32 + 0];
        unsigned int a2 = q32[(size_t)row*32 + 1];
        unsigned int ak = q32[(size_t)row*32 + 2];
        unsigned int b1 = q32[(size_t)row*32 + 3];
        unsigned int b2 = q32[(size_t)row*32 + 4];
        unsigned int bk = q32[(size_t)row*32 + 5];
        unsigned int w1 = a1, wk = ak;             // tie -> half 0 (lower k)
        if (b1 > a1){ w1 = b1; wk = bk; }
        unsigned int w2 = max(max(a2, b2), min(a1, b1));
        k = (int)wk;
        float f1 = __uint_as_float(w1 & 0xFFFFFFE0u);
        float f2 = __uint_as_float(w2 & 0xFFFFFFE0u);
        flag = (f1 - f2) <= FLAG_EPS;
    }
    k = __shfl(k, L & ~3, 64);   // broadcast winner to the row's quad

    // quarter-row gather + squared error
    const float4* xq = (const float4*)(inputs + (size_t)row * DIM + qt * 8);
    const float4* eq = (const float4*)(emb + (size_t)k * DIM + qt * 8);
    float4 x0 = xq[0], x1 = xq[1];
    float4 e0 = eq[0], e1 = eq[1];
    float s;
    {
        float dx = e0.x-x0.x, dy = e0.y-x0.y, dz = e0.z-x0.z, dw = e0.w-x0.w;
        s  = dx*dx + dy*dy + dz*dz + dw*dw;
        dx = e1.x-x1.x; dy = e1.y-x1.y; dz = e1.z-x1.z; dw = e1.w-x1.w;
        s += dx*dx + dy*dy + dz*dz + dw*dw;
    }
    float4* oq = (float4*)(out_q + (size_t)row * DIM + qt * 8);
    oq[0] = e0; oq[1] = e1;        // qt==0 overwrites stash only after reading it
    if (qt == 0){
        out_idx[row] = (float)k;
        if (flag){
            int pos = atomicAdd(cnt, 1);
            if (pos < FLAG_CAP) list[pos] = row;
        }
    }

    // block loss partial: quad -> wave -> block
    s += __shfl_down(s, 1, 64);
    s += __shfl_down(s, 2, 64);
    s += __shfl_down(s, 4, 64);
    s += __shfl_down(s, 8, 64);
    s += __shfl_down(s, 16, 64);
    s += __shfl_down(s, 32, 64);
    __shared__ float sp[4];
    if (L == 0) sp[threadIdx.x >> 6] = s;
    __syncthreads();
    if (threadIdx.x == 0) part[blockIdx.x] = sp[0] + sp[1] + sp[2] + sp[3];
}

// -------- refine: 8 rows/block share one codebook pass, patch + loss sum -----
// block = 1024 threads = 8 row-groups x 128 code-lanes. All groups iterate the
// codebook in the same order -> L1 temporal reuse; traffic = 1MB per block
// instead of 1MB per row (R11's refine re-read 1MB per flagged row: ~840MB).
__global__ __launch_bounds__(1024) void vq_refine(
    const float* __restrict__ inputs, const float* __restrict__ emb,
    float* __restrict__ out_q, float* __restrict__ out_idx,
    const int* __restrict__ list, int* __restrict__ cnt,
    float* __restrict__ corrd, const float* __restrict__ part,
    float* __restrict__ out_loss)
{
    int n = cnt[0]; if (n > FLAG_CAP) n = FLAG_CAP;
    const int g    = threadIdx.x >> 7;   // row group 0..7
    const int l128 = threadIdx.x & 127;
    const int L    = threadIdx.x & 63;
    const int wv   = threadIdx.x >> 6;   // wave 0..15
    __shared__ float swv[16]; __shared__ int swi[16];
    __shared__ int snewk[8];

    for (int jb = blockIdx.x * 8; jb < n; jb += gridDim.x * 8){
        int j = jb + g;
        bool valid = (j < n);
        int row = list[valid ? j : jb];
        const float4* xr = (const float4*)(inputs + (size_t)row * DIM);
        float4 x0 = xr[0], x1 = xr[1], x2 = xr[2], x3 = xr[3];
        float4 x4 = xr[4], x5 = xr[5], x6 = xr[6], x7 = xr[7];
        float bv = -3.0e38f; int bi = 0x7fffffff;
        #pragma unroll 4
        for (int cc = 0; cc < 64; ++cc){
            int c = l128 + (cc << 7);
            const float4* ep = (const float4*)(emb + (size_t)c * DIM);
            float d = dot4(x0, ep[0]) + dot4(x1, ep[1]) + dot4(x2, ep[2]) + dot4(x3, ep[3])
                    + dot4(x4, ep[4]) + dot4(x5, ep[5]) + dot4(x6, ep[6]) + dot4(x7, ep[7]);
            if (d > bv || (d == bv && c < bi)){ bv = d; bi = c; }
        }
        // reduce 128 lanes of the group: wave shuffle, then pair merge in LDS
        #pragma unroll
        for (int off = 32; off; off >>= 1){
            float ov = __shfl_down(bv, off, 64);
            int   oi = __shfl_down(bi, off, 64);
            if (ov > bv || (ov == bv && oi < bi)){ bv = ov; bi = oi; }
        }
        if (L == 0){ swv[wv] = bv; swi[wv] = bi; }
        __syncthreads();
        if (l128 == 0){
            float av = swv[2*g];   int ai = swi[2*g];
            float ov = swv[2*g+1]; int oi = swi[2*g+1];
            if (ov > av || (ov == av && oi < ai)){ av = ov; ai = oi; }
            snewk[g] = ai;
        }
        __syncthreads();
        if (valid){
            int knew = snewk[g];
            int kold = (int)out_idx[row];
            if (l128 < 32){
                float x  = inputs[(size_t)row * DIM + l128];
                float en = emb[(size_t)knew * DIM + l128];
                float eo = emb[(size_t)kold * DIM + l128];
                float d  = (en - x)*(en - x) - (eo - x)*(eo - x);
                #pragma unroll
                for (int off = 16; off; off >>= 1) d += __shfl_down(d, off, 64);
                if (knew != kold) out_q[(size_t)row * DIM + l128] = en;
                if (l128 == 0){
                    corrd[j] = (knew != kold) ? d : 0.0f;
                    if (knew != kold) out_idx[row] = (float)knew;
                }
            }
        }
        __syncthreads();   // protect swv/snewk reuse next pass
    }

    // last-block loss finalize (ticket)
    __shared__ int tkt;
    if (threadIdx.x == 0){
        __threadfence();
        tkt = atomicAdd(cnt + 1, 1);
    }
    __syncthreads();
    if (tkt == (int)gridDim.x - 1){
        __threadfence();
        float s = 0.f;
        if (threadIdx.x < 512) s = part[threadIdx.x];
        for (int j = threadIdx.x; j < n; j += 1024) s += corrd[j];
        #pragma unroll
        for (int off = 32; off; off >>= 1) s += __shfl_down(s, off, 64);
        __shared__ float sp[16];
        if (L == 0) sp[wv] = s;
        __syncthreads();
        if (threadIdx.x == 0){
            float tot = 0.f;
            #pragma unroll
            for (int q = 0; q < 16; q++) tot += sp[q];
            *out_loss = tot * (1.0f / ((float)NROWS * (float)DIM));
        }
    }
}

extern "C" void kernel_launch(void* const* d_in, const int* in_sizes, int n_in,
                              void* d_out, int out_size, void* d_ws, size_t ws_size,
                              hipStream_t stream) {
    const float* inputs = (const float*)d_in[0];
    const float* emb    = (const float*)d_in[1];
    float* out      = (float*)d_out;
    float* out_q    = out;                       // [32768*32]
    float* out_loss = out + (size_t)NROWS * DIM; // [1]
    float* out_idx  = out_loss + 1;              // [32768] as float

    char* ws = (char*)d_ws;
    unsigned short* ehi   = (unsigned short*)(ws + WS_EHI);
    unsigned short* elo   = (unsigned short*)(ws + WS_ELO);
    float*          part  = (float*)(ws + WS_PART);
    int*            cnt   = (int*)(ws + WS_CNT);
    int*            list  = (int*)(ws + WS_LIST);
    float*          corrd = (float*)(ws + WS_CORR);

    vq_prep     <<<dim3(128),  dim3(256),  0, stream>>>(emb, ehi, elo, cnt);
    vq_main_mfma<<<dim3(1024), dim3(512),  0, stream>>>(inputs, ehi, elo, (unsigned int*)out_q);
    vq_gather   <<<dim3(512),  dim3(256),  0, stream>>>(inputs, emb, out_q, out_idx,
                                                        part, cnt, list);
    vq_refine   <<<dim3(128),  dim3(1024), 0, stream>>>(inputs, emb, out_q, out_idx,
                                                        list, cnt, corrd, part, out_loss);
}

// Round 13
// 106.187 us; speedup vs baseline: 2.8185x; 2.8185x over previous
//
#include <hip/hip_runtime.h>

typedef short short8 __attribute__((ext_vector_type(8)));
typedef float f32x4 __attribute__((ext_vector_type(4)));

#define NROWS 32768
#define DIM 32
#define KCODES 8192
#define FLAG_CAP 16384
#define FLAG_EPS 5.0e-4f   // abs margin on packed biased scores: 6-bit pack quantum
                           // 2x1.2e-4 + split err (~3e-5 typ) -> >=2x empirical headroom
#define NBLK 512           // main grid: 512 blocks x 64 rows

// ws layout (bytes)
#define WS_EHI  0
#define WS_ELO  (512*1024)
#define WS_PART (1024*1024)            // 512 floats (main block loss partials)
#define WS_CNT  (WS_PART + 4096)       // cnt[0]=flag count, cnt[1]=refine ticket
#define WS_LIST (WS_CNT + 64)          // FLAG_CAP ints
#define WS_CORR (WS_LIST + FLAG_CAP*4) // FLAG_CAP floats

__device__ __forceinline__ unsigned short bf16_rne(float v){
    unsigned int u = __float_as_uint(v);
    unsigned int r = (u + 0x7fffu + ((u >> 16) & 1u)) >> 16;
    return (unsigned short)r;
}
__device__ __forceinline__ float bf16_to_f(unsigned short h){
    return __uint_as_float(((unsigned int)h) << 16);
}
__device__ __forceinline__ float dot4(const float4& a, const float4& b){
    return fmaf(a.w, b.w, fmaf(a.z, b.z, fmaf(a.y, b.y, a.x * b.x)));
}

// ------------- prep: codebook hi/lo bf16 split (thread = code x quarter) -----
__global__ __launch_bounds__(256) void vq_prep(
    const float* __restrict__ emb,
    unsigned short* __restrict__ ehi, unsigned short* __restrict__ elo,
    int* __restrict__ cnt)
{
    int tid = blockIdx.x * 256 + threadIdx.x;   // 0..32767
    if (tid < 2) cnt[tid] = 0;
    int r  = tid >> 2;
    int qt = tid & 3;
    const float* er = emb + (size_t)r * DIM + qt * 8;
    float4 v0 = *(const float4*)er;
    float4 v1 = *(const float4*)(er + 4);
    float f[8] = {v0.x, v0.y, v0.z, v0.w, v1.x, v1.y, v1.z, v1.w};
    short8 a, b;
    #pragma unroll
    for (int j = 0; j < 8; j++){
        unsigned short h = bf16_rne(f[j]);
        a[j] = (short)h;
        b[j] = (short)bf16_rne(f[j] - bf16_to_f(h));
    }
    *(short8*)(ehi + (size_t)r * DIM + qt * 8) = a;
    *(short8*)(elo + (size_t)r * DIM + qt * 8) = b;
}

// ---------------- main: MFMA argmax + fused gather/loss/flag epilogue --------
// R5-proven geometry: 512 blocks x 8 waves, 64 rows/block, wave w scans codes
// [w*1024,(w+1)*1024) as 64 tiles of 16 (4 rowgroups = 24 MFMA per 4 B-loads).
// Constant bias 16 in MFMA C keeps scores positive (score = 16+dot, |dot| <=
// norm < 16) so packed (score&~63 | 63-t) uints order with first-occurrence
// tie-break; exact ties have margin 0 -> flagged -> refined exactly.
// NOTE (hard-won): min-waves stays 4 (R6: 8 spills); no reg prefetch (R8:
// spill); no global_load_lds DMA (R9: occupancy collapse); grid splitting is
// perf-neutral (R5==R11 main) — per-score throughput limited.
#define PROC(bhv, blv, tcs)                                                      \
  {                                                                              \
    unsigned int tcv = (unsigned int)(tcs);                                      \
    _Pragma("unroll")                                                            \
    for (int rg = 0; rg < 4; ++rg){                                              \
      f32x4 acc = __builtin_amdgcn_mfma_f32_16x16x32_bf16(ahi[rg], bhv, c16, 0, 0, 0); \
      acc = __builtin_amdgcn_mfma_f32_16x16x32_bf16(ahi[rg], blv, acc, 0, 0, 0); \
      acc = __builtin_amdgcn_mfma_f32_16x16x32_bf16(alo[rg], bhv, acc, 0, 0, 0); \
      _Pragma("unroll")                                                          \
      for (int q = 0; q < 4; ++q){                                               \
        unsigned int u = (__float_as_uint(acc[q]) & maskv) | tcv;                \
        int rr = rg * 4 + q;                                                     \
        unsigned int nv2;                                                        \
        asm("v_med3_u32 %0, %1, %2, %3" : "=v"(nv2) : "v"(u), "v"(v1[rr]), "v"(v2[rr])); \
        v2[rr] = nv2;                                                            \
        v1[rr] = max(u, v1[rr]);                                                 \
      }                                                                          \
    }                                                                            \
  }

__global__ __launch_bounds__(512, 4) void vq_main_mfma(
    const float* __restrict__ inputs,
    const unsigned short* __restrict__ ehi,
    const unsigned short* __restrict__ elo,
    const float* __restrict__ emb,
    float* __restrict__ out_q, float* __restrict__ out_idx,
    float* __restrict__ part, int* __restrict__ cnt, int* __restrict__ list)
{
    const int L = threadIdx.x & 63;
    const int w = threadIdx.x >> 6;
    const int rowbase = blockIdx.x * 64;

    __shared__ unsigned int sv1[8][64];
    __shared__ unsigned int sv2[8][64];
    __shared__ int          scol[8][64];

    // A fragments (all waves load the same 64 rows)
    short8 ahi[4], alo[4];
    #pragma unroll
    for (int rg = 0; rg < 4; ++rg){
        const float* xr = inputs + (size_t)(rowbase + rg*16 + (L & 15)) * DIM + (L >> 4) * 8;
        float4 p0 = *(const float4*)xr;
        float4 p1 = *(const float4*)(xr + 4);
        float f[8] = {p0.x, p0.y, p0.z, p0.w, p1.x, p1.y, p1.z, p1.w};
        short8 h, l;
        #pragma unroll
        for (int i = 0; i < 8; i++){
            unsigned short hb = bf16_rne(f[i]);
            h[i] = (short)hb;
            l[i] = (short)bf16_rne(f[i] - bf16_to_f(hb));
        }
        ahi[rg] = h; alo[rg] = l;
    }

    const f32x4 c16 = {16.0f, 16.0f, 16.0f, 16.0f};

    unsigned int maskv = 0xFFFFFFC0u;   // 6-bit counter field (t < 64)
    asm("" : "+v"(maskv));   // pin mask in VGPR so (x & m) | t fuses to v_and_or_b32

    unsigned int v1[16], v2[16];
    #pragma unroll
    for (int r = 0; r < 16; r++){ v1[r] = 0u; v2[r] = 0u; }

    const int c0 = w * 1024;
    const unsigned short* ehp = ehi + (size_t)(c0 + (L & 15)) * DIM + (L >> 4) * 8;
    const unsigned short* elp = elo + (size_t)(c0 + (L & 15)) * DIM + (L >> 4) * 8;

    for (int t = 0; t < 64; t += 2){
        short8 b0h = *(const short8*)(ehp);
        short8 b0l = *(const short8*)(elp);
        short8 b1h = *(const short8*)(ehp + 512);
        short8 b1l = *(const short8*)(elp + 512);
        ehp += 1024; elp += 1024;
        PROC(b0h, b0l, 63 - t);
        PROC(b1h, b1l, 62 - t);
    }

    // in-register reduction over the 16 cols (lane&15), exact top-2 merge
    unsigned int p1[16];
    #pragma unroll
    for (int r = 0; r < 16; r++) p1[r] = v1[r];
    #pragma unroll
    for (int m = 1; m < 16; m <<= 1){
        #pragma unroll
        for (int r = 0; r < 16; r++){
            unsigned int ov1 = __shfl_xor(v1[r], m, 64);
            unsigned int ov2 = __shfl_xor(v2[r], m, 64);
            unsigned int mn = min(v1[r], ov1);
            v2[r] = max(max(v2[r], ov2), mn);
            v1[r] = max(v1[r], ov1);
        }
    }
    // recover winning col via ballot (lowest matching lane = lowest col = first occurrence)
    int colr[16];
    #pragma unroll
    for (int r = 0; r < 16; r++){
        unsigned long long bm = __ballot(p1[r] == v1[r]);
        unsigned int grp = (unsigned int)((bm >> ((L >> 4) << 4)) & 0xFFFFull);
        colr[r] = __ffs(grp) - 1;
    }

    if ((L & 15) == 0){
        #pragma unroll
        for (int rg = 0; rg < 4; ++rg){
            #pragma unroll
            for (int q = 0; q < 4; ++q){
                int row = rg*16 + (L >> 4)*4 + q;   // C row = (lane>>4)*4 + reg
                sv1[w][row] = v1[rg*4 + q];
                sv2[w][row] = v2[rg*4 + q];
                scol[w][row] = colr[rg*4 + q];
            }
        }
    }
    __syncthreads();

    // epilogue (threads 0..63): merge 8 wave-slices, gather, loss, flag
    if (threadIdx.x < 64){
        int r = threadIdx.x;
        unsigned int b1 = 0u, b2 = 0u; int bw = 0, bc = 0;
        #pragma unroll
        for (int s = 0; s < 8; ++s){
            unsigned int u1 = sv1[s][r];
            unsigned int u2 = sv2[s][r];
            unsigned int mn = min(b1, u1);
            b2 = max(max(b2, u2), mn);
            bool g = u1 > b1;
            if (g){ b1 = u1; bw = s; bc = scol[s][r]; }
        }
        int t = 63 - (int)(b1 & 63u);
        int k = bw*1024 + t*16 + bc;
        int row = rowbase + r;
        out_idx[row] = (float)k;

        // gather code row, write quantized output, per-row squared error
        const float4* ep = (const float4*)(emb + (size_t)k * DIM);
        const float4* xr = (const float4*)(inputs + (size_t)row * DIM);
        float4* oq = (float4*)(out_q + (size_t)row * DIM);
        float s = 0.f;
        #pragma unroll
        for (int i = 0; i < 8; i++){
            float4 q = ep[i], x = xr[i];
            oq[i] = q;
            float dx = q.x - x.x, dy = q.y - x.y, dz = q.z - x.z, dw = q.w - x.w;
            s += dx*dx + dy*dy + dz*dz + dw*dw;
        }

        // flag near-ties for exact fp32 refinement (absolute margin)
        float f1 = __uint_as_float(b1 & 0xFFFFFFC0u);
        float f2 = __uint_as_float(b2 & 0xFFFFFFC0u);
        if (f1 - f2 <= FLAG_EPS){
            int pos = atomicAdd(cnt, 1);
            if (pos < FLAG_CAP) list[pos] = row;
        }

        // 64-lane reduction of the block's loss partial
        #pragma unroll
        for (int off = 32; off; off >>= 1) s += __shfl_down(s, off, 64);
        if (r == 0) part[blockIdx.x] = s;
    }
}

// -------- refine: exact fp32 argmax for flagged rows + patch + loss sum ------
// R11-proven shape: 256 blocks x 1024 threads, one row at a time per block.
__global__ __launch_bounds__(1024) void vq_refine(
    const float* __restrict__ inputs, const float* __restrict__ emb,
    float* __restrict__ out_q, float* __restrict__ out_idx,
    const int* __restrict__ list, int* __restrict__ cnt,
    float* __restrict__ corrd, const float* __restrict__ part,
    float* __restrict__ out_loss)
{
    int n = cnt[0]; if (n > FLAG_CAP) n = FLAG_CAP;
    const int L = threadIdx.x & 63;
    const int wv = threadIdx.x >> 6;
    __shared__ float swv[16]; __shared__ int swi[16];
    __shared__ int sbi;
    for (int j = blockIdx.x; j < n; j += gridDim.x){
        int row = list[j];
        const float4* xr = (const float4*)(inputs + (size_t)row * DIM);
        float4 x0 = xr[0], x1 = xr[1], x2 = xr[2], x3 = xr[3];
        float4 x4 = xr[4], x5 = xr[5], x6 = xr[6], x7 = xr[7];
        float bv = -3.0e38f; int bi = 0x7fffffff;
        for (int c = threadIdx.x; c < KCODES; c += 1024){
            const float4* ep = (const float4*)(emb + (size_t)c * DIM);
            float d = dot4(x0, ep[0]) + dot4(x1, ep[1]) + dot4(x2, ep[2]) + dot4(x3, ep[3])
                    + dot4(x4, ep[4]) + dot4(x5, ep[5]) + dot4(x6, ep[6]) + dot4(x7, ep[7]);
            if (d > bv || (d == bv && c < bi)){ bv = d; bi = c; }
        }
        #pragma unroll
        for (int off = 32; off; off >>= 1){
            float ov = __shfl_down(bv, off, 64);
            int   oi = __shfl_down(bi, off, 64);
            if (ov > bv || (ov == bv && oi < bi)){ bv = ov; bi = oi; }
        }
        if (L == 0){ swv[wv] = bv; swi[wv] = bi; }
        __syncthreads();
        if (threadIdx.x == 0){
            #pragma unroll
            for (int q = 1; q < 16; q++){
                if (swv[q] > bv || (swv[q] == bv && swi[q] < bi)){ bv = swv[q]; bi = swi[q]; }
            }
            sbi = bi;
        }
        __syncthreads();
        int knew = sbi;
        int kold = (int)out_idx[row];
        if (threadIdx.x < 32){
            float x  = inputs[(size_t)row * DIM + threadIdx.x];
            float en = emb[(size_t)knew * DIM + threadIdx.x];
            float eo = emb[(size_t)kold * DIM + threadIdx.x];
            float d  = (en - x)*(en - x) - (eo - x)*(eo - x);
            #pragma unroll
            for (int off = 16; off; off >>= 1) d += __shfl_down(d, off, 64);
            if (knew != kold) out_q[(size_t)row * DIM + threadIdx.x] = en;
            if (threadIdx.x == 0){
                corrd[j] = (knew != kold) ? d : 0.0f;
                if (knew != kold) out_idx[row] = (float)knew;
            }
        }
        __syncthreads();
    }

    // last-block loss finalize (ticket)
    __shared__ int tkt;
    if (threadIdx.x == 0){
        __threadfence();
        tkt = atomicAdd(cnt + 1, 1);
    }
    __syncthreads();
    if (tkt == (int)gridDim.x - 1){
        __threadfence();
        float s = 0.f;
        if (threadIdx.x < NBLK) s = part[threadIdx.x];
        for (int j = threadIdx.x; j < n; j += 1024) s += corrd[j];
        #pragma unroll
        for (int off = 32; off; off >>= 1) s += __shfl_down(s, off, 64);
        __shared__ float sp[16];
        if (L == 0) sp[wv] = s;
        __syncthreads();
        if (threadIdx.x == 0){
            float tot = 0.f;
            #pragma unroll
            for (int q = 0; q < 16; q++) tot += sp[q];
            *out_loss = tot * (1.0f / ((float)NROWS * (float)DIM));
        }
    }
}

extern "C" void kernel_launch(void* const* d_in, const int* in_sizes, int n_in,
                              void* d_out, int out_size, void* d_ws, size_t ws_size,
                              hipStream_t stream) {
    const float* inputs = (const float*)d_in[0];
    const float* emb    = (const float*)d_in[1];
    float* out      = (float*)d_out;
    float* out_q    = out;                       // [32768*32]
    float* out_loss = out + (size_t)NROWS * DIM; // [1]
    float* out_idx  = out_loss + 1;              // [32768] as float

    char* ws = (char*)d_ws;
    unsigned short* ehi   = (unsigned short*)(ws + WS_EHI);
    unsigned short* elo   = (unsigned short*)(ws + WS_ELO);
    float*          part  = (float*)(ws + WS_PART);
    int*            cnt   = (int*)(ws + WS_CNT);
    int*            list  = (int*)(ws + WS_LIST);
    float*          corrd = (float*)(ws + WS_CORR);

    vq_prep     <<<dim3(128),  dim3(256),  0, stream>>>(emb, ehi, elo, cnt);
    vq_main_mfma<<<dim3(NBLK), dim3(512),  0, stream>>>(inputs, ehi, elo, emb,
                                                        out_q, out_idx, part, cnt, list);
    vq_refine   <<<dim3(256),  dim3(1024), 0, stream>>>(inputs, emb, out_q, out_idx,
                                                        list, cnt, corrd, part, out_loss);
}